// Round 2
// baseline (160.359 us; speedup 1.0000x reference)
//
#include <hip/hip_runtime.h>
#include <hip/hip_bf16.h>

typedef __bf16 bf16x8 __attribute__((ext_vector_type(8)));
typedef float  f32x4  __attribute__((ext_vector_type(4)));

#define NEG_BIG (-1e10f)

constexpr int FUSED_N = 4 * 32 * 32 * 256;  // 1048576

// ---------------------------------------------------------------------------
// Inputs are fp32 (per reference). No fp32 MFMA on CDNA4, so we split each
// operand x = hi + lo (bf16 RNE + bf16 residual) and compute
//   A*B ~= Ah*Bh + Ah*Bl + Al*Bh      (dropped Al*Bl term: ~2^-18 relative)
// which is fp32-class accuracy at 3x bf16 MFMA cost.
// ---------------------------------------------------------------------------

// Swizzled granule address inside a 64-row x 16-granule (64x128 bf16) chunk.
// 16B-granule XOR swizzle: staging writes and MFMA fragment reads both land
// at the uniform bank floor. Returns ELEMENT offset.
__device__ __forceinline__ int swz16(int row, int g) {
    return (row * 16 + (g ^ (row & 15))) * 8;
}

// Stage a 64x128 bf16 chunk (source row stride 256 elems) into swizzled LDS.
__device__ __forceinline__ void stage_bf16(const __bf16* __restrict__ src,
                                           __bf16* sdst, int tid) {
#pragma unroll
    for (int it = 0; it < 4; ++it) {
        int idx = it * 256 + tid;        // 1024 granules
        int row = idx >> 4, gg = idx & 15;
        *(uint4*)&sdst[swz16(row, gg)] = *(const uint4*)&src[row * 256 + gg * 8];
    }
}

// Stage a 64x128 fp32 chunk (row stride 256), converting to hi/lo bf16 LDS.
__device__ __forceinline__ void stage_cvt(const float* __restrict__ src,
                                          __bf16* sh, __bf16* sl, int tid) {
#pragma unroll
    for (int it = 0; it < 4; ++it) {
        int idx = it * 256 + tid;
        int row = idx >> 4, gg = idx & 15;
        const float* p = &src[row * 256 + gg * 8];
        float4 v0 = *(const float4*)p;
        float4 v1 = *(const float4*)(p + 4);
        float f[8] = {v0.x, v0.y, v0.z, v0.w, v1.x, v1.y, v1.z, v1.w};
        union { __bf16 b[8]; uint4 u; } H, L;
#pragma unroll
        for (int k = 0; k < 8; ++k) {
            __bf16 h = (__bf16)f[k];
            H.b[k] = h;
            L.b[k] = (__bf16)(f[k] - (float)h);
        }
        int o = swz16(row, gg);
        *(uint4*)&sh[o] = H.u;
        *(uint4*)&sl[o] = L.u;
    }
}

// D(64x64) += A(64x128) @ B(64x128)^T with hi/lo split (3 MFMA terms).
// Verified layouts (learn_hip m89/m91/m120):
//   A-frag: A[m=lane&15][k=(lane>>4)*8 + jj]
//   B-frag: B[n=lane&15][k=(lane>>4)*8 + jj]
//   C/D   : col = lane&15, row = (lane>>4)*4 + reg
__device__ __forceinline__ void mfma3_chunk(const __bf16* sAh, const __bf16* sAl,
                                            const __bf16* sBh, const __bf16* sBl,
                                            int lane, int wave, f32x4 acc[4]) {
    const int m = lane & 15, quad = lane >> 4;
    const int arow = wave * 16 + m;
#pragma unroll
    for (int k0 = 0; k0 < 4; ++k0) {
        const int ag = k0 * 4 + quad;
        bf16x8 ah = *(const bf16x8*)&sAh[swz16(arow, ag)];
        bf16x8 al = *(const bf16x8*)&sAl[swz16(arow, ag)];
#pragma unroll
        for (int n = 0; n < 4; ++n) {
            const int bo = swz16(n * 16 + m, ag);
            bf16x8 bh = *(const bf16x8*)&sBh[bo];
            bf16x8 bl = *(const bf16x8*)&sBl[bo];
            acc[n] = __builtin_amdgcn_mfma_f32_16x16x32_bf16(ah, bh, acc[n], 0, 0, 0);
            acc[n] = __builtin_amdgcn_mfma_f32_16x16x32_bf16(ah, bl, acc[n], 0, 0, 0);
            acc[n] = __builtin_amdgcn_mfma_f32_16x16x32_bf16(al, bh, acc[n], 0, 0, 0);
        }
    }
}

// fp32 -> hi/lo bf16 planes, float4-vectorized. n4 = element count / 4.
__global__ __launch_bounds__(256) void convert_kernel(
    const float* __restrict__ src, __bf16* __restrict__ hi,
    __bf16* __restrict__ lo, int n4) {
    int i = blockIdx.x * 256 + threadIdx.x;
    if (i >= n4) return;
    float4 v = ((const float4*)src)[i];
    float f[4] = {v.x, v.y, v.z, v.w};
    union { __bf16 b[4]; uint2 u; } H, L;
#pragma unroll
    for (int k = 0; k < 4; ++k) {
        __bf16 h = (__bf16)f[k];
        H.b[k] = h;
        L.b[k] = (__bf16)(f[k] - (float)h);
    }
    *(uint2*)&hi[i * 4] = H.u;
    *(uint2*)&lo[i * 4] = L.u;
}

// P[8192,256] = X[8192,256] @ W[256,256]^T, split-MFMA; emits hi/lo planes.
template <bool CVT>
__global__ __launch_bounds__(256, 2) void proj_kernel(
    const float* __restrict__ Xf, const float* __restrict__ Wf,
    const __bf16* __restrict__ Xh, const __bf16* __restrict__ Xl,
    const __bf16* __restrict__ Wh, const __bf16* __restrict__ Wl,
    __bf16* __restrict__ Ph, __bf16* __restrict__ Pl) {
    __shared__ __align__(16) __bf16 smem[4 * 64 * 128];  // 64 KB
    __bf16* sAh = smem;
    __bf16* sAl = smem + 8192;
    __bf16* sBh = smem + 16384;
    __bf16* sBl = smem + 24576;
    const int tid = threadIdx.x;
    const int rb = blockIdx.x >> 2, gb = blockIdx.x & 3;
    const int lane = tid & 63, wave = tid >> 6;

    f32x4 acc[4];
    const f32x4 z = {0.f, 0.f, 0.f, 0.f};
#pragma unroll
    for (int n = 0; n < 4; ++n) acc[n] = z;

#pragma unroll
    for (int kc = 0; kc < 2; ++kc) {
        if (kc) __syncthreads();  // prior MFMA reads done before restage
        if (CVT) {
            stage_cvt(Xf + rb * 64 * 256 + kc * 128, sAh, sAl, tid);
            stage_cvt(Wf + gb * 64 * 256 + kc * 128, sBh, sBl, tid);
        } else {
            stage_bf16(Xh + rb * 64 * 256 + kc * 128, sAh, tid);
            stage_bf16(Xl + rb * 64 * 256 + kc * 128, sAl, tid);
            stage_bf16(Wh + gb * 64 * 256 + kc * 128, sBh, tid);
            stage_bf16(Wl + gb * 64 * 256 + kc * 128, sBl, tid);
        }
        __syncthreads();
        mfma3_chunk(sAh, sAl, sBh, sBl, lane, wave, acc);
    }

    const int m = lane & 15, quad = lane >> 4;
#pragma unroll
    for (int n = 0; n < 4; ++n)
#pragma unroll
        for (int r = 0; r < 4; ++r) {
            int row = rb * 64 + wave * 16 + quad * 4 + r;
            int col = gb * 64 + n * 16 + m;
            float v = acc[n][r];
            __bf16 h = (__bf16)v;
            Ph[row * 256 + col] = h;
            Pl[row * 256 + col] = (__bf16)(v - (float)h);
        }
}

// One block per (b,i,j): scores = P(b,i) @ X(b,j)^T via split MFMA,
// sigmoid -> att (fp32 out); then w[t] = sum_s aself[s]*att[s,t];
// fused[h] = sum_t w[t]*X[t,h].
template <bool CVT>
__global__ __launch_bounds__(256, 2) void main_kernel(
    const float* __restrict__ Xf, const float* __restrict__ maskf,
    const float* __restrict__ aselff,
    const __bf16* __restrict__ Xh, const __bf16* __restrict__ Xl,
    const __bf16* __restrict__ Ph, const __bf16* __restrict__ Pl,
    float* __restrict__ out) {
    __shared__ __align__(16) __bf16 smem[4 * 64 * 128];  // 64 KB
    __bf16* sPh = smem;
    __bf16* sPl = smem + 8192;
    __bf16* sXh = smem + 16384;
    __bf16* sXl = smem + 24576;
    const int tid = threadIdx.x;
    const int j = blockIdx.x & 31;
    const int i = (blockIdx.x >> 5) & 31;
    const int b = blockIdx.x >> 10;
    const int lane = tid & 63, wave = tid >> 6;
    const int pr = (b * 32 + i) * 64 * 256;
    const int xr = (b * 32 + j) * 64 * 256;

    f32x4 acc[4];
    const f32x4 z = {0.f, 0.f, 0.f, 0.f};
#pragma unroll
    for (int n = 0; n < 4; ++n) acc[n] = z;

#pragma unroll
    for (int kc = 0; kc < 2; ++kc) {
        if (kc) __syncthreads();
        stage_bf16(Ph + pr + kc * 128, sPh, tid);
        stage_bf16(Pl + pr + kc * 128, sPl, tid);
        if (CVT) {
            stage_cvt(Xf + xr + kc * 128, sXh, sXl, tid);
        } else {
            stage_bf16(Xh + xr + kc * 128, sXh, tid);
            stage_bf16(Xl + xr + kc * 128, sXl, tid);
        }
        __syncthreads();
        mfma3_chunk(sPh, sPl, sXh, sXl, lane, wave, acc);
    }

    // mask + sigmoid; write att (fp32); keep fp32 att in regs
    const int m = lane & 15, quad = lane >> 4;
    const float* mrow = maskf + (b * 32 + j) * 64;
    float att_v[16];
    float* outA = out + FUSED_N + ((b * 32 + i) * 32 + j) * 4096;
#pragma unroll
    for (int n = 0; n < 4; ++n) {
        const int t = n * 16 + m;
        const float madd = (1.0f - mrow[t]) * NEG_BIG;
#pragma unroll
        for (int r = 0; r < 4; ++r) {
            const int s = wave * 16 + quad * 4 + r;
            float x = acc[n][r] + madd;
            float a = 1.0f / (1.0f + __expf(-x));
            att_v[n * 4 + r] = a;
            outA[s * 64 + t] = a;
        }
    }

    __syncthreads();               // all MFMA LDS reads done -> reuse smem
    float* attS = (float*)smem;    // 64 x 65 fp32 = 16.6 KB
#pragma unroll
    for (int n = 0; n < 4; ++n)
#pragma unroll
        for (int r = 0; r < 4; ++r)
            attS[(wave * 16 + quad * 4 + r) * 65 + (n * 16 + m)] = att_v[n * 4 + r];
    __syncthreads();

    float* s_w = attS + 64 * 65;   // 64 floats
    if (tid < 64) {
        const float* arow = aselff + (b * 32 + i) * 64;
        float acw = 0.f;
        for (int s = 0; s < 64; ++s) acw += arow[s] * attS[s * 65 + tid];
        s_w[tid] = acw;
    }
    __syncthreads();

    // fused[h]: X tile re-read from global (L2-hot, coalesced over h=tid)
    const float* Xg = Xf + xr;
    float acf = 0.f;
#pragma unroll 8
    for (int t = 0; t < 64; ++t) acf += s_w[t] * Xg[t * 256 + tid];
    out[((b * 32 + i) * 32 + j) * 256 + tid] = acf;
}

extern "C" void kernel_launch(void* const* d_in, const int* in_sizes, int n_in,
                              void* d_out, int out_size, void* d_ws, size_t ws_size,
                              hipStream_t stream) {
    const float* X     = (const float*)d_in[0];  // [4,32,64,256] fp32
    const float* mask  = (const float*)d_in[1];  // [4,32,64]
    const float* aself = (const float*)d_in[2];  // [4,32,64]
    const float* W     = (const float*)d_in[3];  // [256,256]
    float* out = (float*)d_out;

    __bf16* ws = (__bf16*)d_ws;
    const size_t NX = 2097152, NW = 65536;
    const size_t need_full = (4 * NX + 2 * NW) * sizeof(__bf16);  // ~16.3 MB

    if (ws_size >= need_full) {
        __bf16* Xh = ws;
        __bf16* Xl = Xh + NX;
        __bf16* Ph = Xl + NX;
        __bf16* Pl = Ph + NX;
        __bf16* Wh = Pl + NX;
        __bf16* Wl = Wh + NW;
        convert_kernel<<<dim3(2048), dim3(256), 0, stream>>>(X, Xh, Xl, (int)(NX / 4));
        convert_kernel<<<dim3(64), dim3(256), 0, stream>>>(W, Wh, Wl, (int)(NW / 4));
        proj_kernel<false><<<dim3(512), dim3(256), 0, stream>>>(
            X, W, Xh, Xl, Wh, Wl, Ph, Pl);
        main_kernel<false><<<dim3(4096), dim3(256), 0, stream>>>(
            X, mask, aself, Xh, Xl, Ph, Pl, out);
    } else {
        // Low-workspace tier: only P planes in ws; convert X/W during staging.
        __bf16* Ph = ws;
        __bf16* Pl = Ph + NX;
        proj_kernel<true><<<dim3(512), dim3(256), 0, stream>>>(
            X, W, nullptr, nullptr, nullptr, nullptr, Ph, Pl);
        main_kernel<true><<<dim3(4096), dim3(256), 0, stream>>>(
            X, mask, aself, nullptr, nullptr, Ph, Pl, out);
    }
}